// Round 1
// baseline (340.041 us; speedup 1.0000x reference)
//
#include <hip/hip_runtime.h>

typedef float floatx4 __attribute__((ext_vector_type(4)));

struct RGB { float r, g, b; };

__device__ __forceinline__ float clamp01(float x) {
    return fminf(fmaxf(x, 0.0f), 1.0f);
}

// Per-pixel RGB -> HSV -> (hue shift, sat scale) -> RGB.
// Algebraically simplified vs the JAX reference (tolerance 2e-2 allows
// v_rcp_f32 instead of exact divides, and the fmod chain collapses since
// hraw is provably in (-1, 5)).
__device__ __forceinline__ RGB hsv_px(float r, float g, float b,
                                      float dh, float ds) {
    float maxc = fmaxf(r, fmaxf(g, b));
    float minc = fminf(r, fminf(g, b));
    float cr   = maxc - minc;
    bool  eq   = (cr == 0.0f);
    // fast reciprocals (~1 ulp); eq-guarded so gray pixels give s=0, h0=0
    float inv  = eq ? 0.0f : __builtin_amdgcn_rcpf(cr);
    float s    = eq ? 0.0f : cr * __builtin_amdgcn_rcpf(maxc);

    // hraw in sixths: r-max -> (g-b)/cr in [-1,1]; g-max -> 2+(b-r)/cr in [1,3];
    // b-max -> 4+(r-g)/cr in [3,5].
    float h0 = (maxc == r) ? (g - b) * inv
             : (maxc == g) ? fmaf(b - r, inv, 2.0f)
                           : fmaf(r - g, inv, 4.0f);

    // mod(mod(h0,6)/6 + dh, 1) == frac(h0/6 + dh)
    float hh = fmaf(h0, (1.0f / 6.0f), dh);
    hh -= floorf(hh);                       // in [0,1)
    s = clamp01(s * ds);

    float v  = maxc;
    float h6 = hh * 6.0f;
    float fi = floorf(h6);
    float f  = h6 - fi;
    int   i  = (int)fi;
    if (i >= 6) i -= 6;                     // reference's i % 6 guard
    float p = clamp01(v * (1.0f - s));
    float q = clamp01(v * fmaf(-s, f, 1.0f));
    float t = clamp01(v * fmaf(-s, 1.0f - f, 1.0f));
    // r = sel(v,q,p,p,t,v); g = sel(t,v,v,q,p,p); b = sel(p,p,t,v,v,q)
    RGB o;
    o.r = (i == 0 || i == 5) ? v : (i == 1) ? q : (i == 4) ? t : p;
    o.g = (i == 1 || i == 2) ? v : (i == 0) ? t : (i == 3) ? q : p;
    o.b = (i == 3 || i == 4) ? v : (i == 2) ? t : (i == 5) ? q : p;
    return o;
}

__device__ __forceinline__ void hsv_quad(floatx4 r4, floatx4 g4, floatx4 b4,
                                         float dh, float ds,
                                         floatx4& ro4, floatx4& go4, floatx4& bo4) {
    {
        RGB o = hsv_px(r4.x, g4.x, b4.x, dh, ds);
        ro4.x = o.r; go4.x = o.g; bo4.x = o.b;
    }
    {
        RGB o = hsv_px(r4.y, g4.y, b4.y, dh, ds);
        ro4.y = o.r; go4.y = o.g; bo4.y = o.b;
    }
    {
        RGB o = hsv_px(r4.z, g4.z, b4.z, dh, ds);
        ro4.z = o.r; go4.z = o.g; bo4.z = o.b;
    }
    {
        RGB o = hsv_px(r4.w, g4.w, b4.w, dh, ds);
        ro4.w = o.r; go4.w = o.g; bo4.w = o.b;
    }
}

// Each block handles 512 consecutive quads (2048 floats) of ONE image's
// plane-space: thread t owns quads {blk*512 + t, blk*512 + t + 256}, so
// every load/store instruction is a fully dense 1024B span per wave.
// b (image index) is derived from blockIdx only -> stays scalar, and the
// params reads become s_load_dword instead of per-thread VMEM.
__global__ __launch_bounds__(256)
void AdjustHueSaturation_60455959658579_kernel(const float* __restrict__ img,
                                               const float* __restrict__ params,
                                               float* __restrict__ out,
                                               int HW, int quads, int blocksPerImg) {
    int b   = (int)blockIdx.x / blocksPerImg;           // wave-uniform -> SGPR
    int blk = (int)blockIdx.x - b * blocksPerImg;
    int q0  = blk * 512 + (int)threadIdx.x;
    int q1  = q0 + 256;

    float dh = params[2 * b];                           // scalar loads
    float ds = params[2 * b + 1];

    const float* ip = img + (size_t)b * 3u * (size_t)HW;
    float*       op = out + (size_t)b * 3u * (size_t)HW;

    bool ok0 = (q0 < quads);
    bool ok1 = (q1 < quads);

    floatx4 r0{}, g0{}, b0{}, r1{}, g1{}, b1{};
    size_t base0 = (size_t)q0 * 4u;
    size_t base1 = (size_t)q1 * 4u;

    // Issue all six 16B loads up front (restrict lets them overlap).
    if (ok0) {
        r0 = *reinterpret_cast<const floatx4*>(ip + base0);
        g0 = *reinterpret_cast<const floatx4*>(ip + base0 + (size_t)HW);
        b0 = *reinterpret_cast<const floatx4*>(ip + base0 + 2 * (size_t)HW);
    }
    if (ok1) {
        r1 = *reinterpret_cast<const floatx4*>(ip + base1);
        g1 = *reinterpret_cast<const floatx4*>(ip + base1 + (size_t)HW);
        b1 = *reinterpret_cast<const floatx4*>(ip + base1 + 2 * (size_t)HW);
    }

    floatx4 ro0, go0, bo0, ro1, go1, bo1;
    hsv_quad(r0, g0, b0, dh, ds, ro0, go0, bo0);
    hsv_quad(r1, g1, b1, dh, ds, ro1, go1, bo1);

    if (ok0) {
        __builtin_nontemporal_store(ro0, reinterpret_cast<floatx4*>(op + base0));
        __builtin_nontemporal_store(go0, reinterpret_cast<floatx4*>(op + base0 + (size_t)HW));
        __builtin_nontemporal_store(bo0, reinterpret_cast<floatx4*>(op + base0 + 2 * (size_t)HW));
    }
    if (ok1) {
        __builtin_nontemporal_store(ro1, reinterpret_cast<floatx4*>(op + base1));
        __builtin_nontemporal_store(go1, reinterpret_cast<floatx4*>(op + base1 + (size_t)HW));
        __builtin_nontemporal_store(bo1, reinterpret_cast<floatx4*>(op + base1 + 2 * (size_t)HW));
    }
}

extern "C" void kernel_launch(void* const* d_in, const int* in_sizes, int n_in,
                              void* d_out, int out_size, void* d_ws, size_t ws_size,
                              hipStream_t stream) {
    const float* img    = (const float*)d_in[0];
    const float* params = (const float*)d_in[1];
    float*       out    = (float*)d_out;

    int total_elems = in_sizes[0];          // B*3*H*W
    int Bn          = in_sizes[1] / 2;      // 64
    int HW          = total_elems / (3 * Bn);
    int quads       = HW / 4;               // HW divisible by 4 (W=512)
    int blocksPerImg = (quads + 511) / 512; // 512 quads per block (2/thread)

    int grid = Bn * blocksPerImg;           // 64 * 128 = 8192 for 512x512
    AdjustHueSaturation_60455959658579_kernel<<<grid, 256, 0, stream>>>(
        img, params, out, HW, quads, blocksPerImg);
}

// Round 2
// 314.936 us; speedup vs baseline: 1.0797x; 1.0797x over previous
//
#include <hip/hip_runtime.h>

typedef float floatx4 __attribute__((ext_vector_type(4)));

struct RGB { float r, g, b; };

__device__ __forceinline__ float clamp01(float x) {
    return fminf(fmaxf(x, 0.0f), 1.0f);
}

// Per-pixel RGB -> HSV -> (hue shift, sat scale) -> RGB.
// Algebraically simplified vs the JAX reference (tolerance 2e-2 allows
// v_rcp_f32 instead of exact divides, and the fmod chain collapses since
// hraw is provably in (-1, 5)).
__device__ __forceinline__ RGB hsv_px(float r, float g, float b,
                                      float dh, float ds) {
    float maxc = fmaxf(r, fmaxf(g, b));
    float minc = fminf(r, fminf(g, b));
    float cr   = maxc - minc;
    bool  eq   = (cr == 0.0f);
    // fast reciprocals (~1 ulp); eq-guarded so gray pixels give s=0, h0=0
    float inv  = eq ? 0.0f : __builtin_amdgcn_rcpf(cr);
    float s    = eq ? 0.0f : cr * __builtin_amdgcn_rcpf(maxc);

    // hraw in sixths: r-max -> (g-b)/cr in [-1,1]; g-max -> 2+(b-r)/cr in [1,3];
    // b-max -> 4+(r-g)/cr in [3,5].
    float h0 = (maxc == r) ? (g - b) * inv
             : (maxc == g) ? fmaf(b - r, inv, 2.0f)
                           : fmaf(r - g, inv, 4.0f);

    // mod(mod(h0,6)/6 + dh, 1) == frac(h0/6 + dh)
    float hh = fmaf(h0, (1.0f / 6.0f), dh);
    hh -= floorf(hh);                       // in [0,1)
    s = clamp01(s * ds);

    float v  = maxc;
    float h6 = hh * 6.0f;
    float fi = floorf(h6);
    float f  = h6 - fi;
    int   i  = (int)fi;
    if (i >= 6) i -= 6;                     // reference's i % 6 guard
    float p = clamp01(v * (1.0f - s));
    float q = clamp01(v * fmaf(-s, f, 1.0f));
    float t = clamp01(v * fmaf(-s, 1.0f - f, 1.0f));
    // r = sel(v,q,p,p,t,v); g = sel(t,v,v,q,p,p); b = sel(p,p,t,v,v,q)
    RGB o;
    o.r = (i == 0 || i == 5) ? v : (i == 1) ? q : (i == 4) ? t : p;
    o.g = (i == 1 || i == 2) ? v : (i == 0) ? t : (i == 3) ? q : p;
    o.b = (i == 3 || i == 4) ? v : (i == 2) ? t : (i == 5) ? q : p;
    return o;
}

// One 16B quad per plane per thread (the verified-fast structure from the
// prior session), with the only changes being scalar-path cleanups:
//  - image index b derived from blockIdx (wave-uniform -> SALU magic-div),
//    so params reads become s_load instead of per-thread VMEM
//  - no per-thread integer division
// NT hints kept on BOTH loads and stores (removing them regressed R0->R1).
__global__ __launch_bounds__(256)
void AdjustHueSaturation_60455959658579_kernel(const float* __restrict__ img,
                                               const float* __restrict__ params,
                                               float* __restrict__ out,
                                               int HW, int quads, int blocksPerImg) {
    int b   = (int)blockIdx.x / blocksPerImg;       // wave-uniform -> SGPR
    int blk = (int)blockIdx.x - b * blocksPerImg;
    int q   = blk * 256 + (int)threadIdx.x;         // quad index within image
    if (q >= quads) return;                         // uniform for full blocks

    float dh = params[2 * b];                       // scalar loads
    float ds = params[2 * b + 1];

    size_t base = (size_t)b * 3u * (size_t)HW + (size_t)q * 4u;

    floatx4 r4 = __builtin_nontemporal_load(
        reinterpret_cast<const floatx4*>(img + base));
    floatx4 g4 = __builtin_nontemporal_load(
        reinterpret_cast<const floatx4*>(img + base + (size_t)HW));
    floatx4 b4 = __builtin_nontemporal_load(
        reinterpret_cast<const floatx4*>(img + base + 2 * (size_t)HW));

    floatx4 ro4, go4, bo4;
    {
        RGB o = hsv_px(r4.x, g4.x, b4.x, dh, ds);
        ro4.x = o.r; go4.x = o.g; bo4.x = o.b;
    }
    {
        RGB o = hsv_px(r4.y, g4.y, b4.y, dh, ds);
        ro4.y = o.r; go4.y = o.g; bo4.y = o.b;
    }
    {
        RGB o = hsv_px(r4.z, g4.z, b4.z, dh, ds);
        ro4.z = o.r; go4.z = o.g; bo4.z = o.b;
    }
    {
        RGB o = hsv_px(r4.w, g4.w, b4.w, dh, ds);
        ro4.w = o.r; go4.w = o.g; bo4.w = o.b;
    }

    __builtin_nontemporal_store(ro4, reinterpret_cast<floatx4*>(out + base));
    __builtin_nontemporal_store(go4, reinterpret_cast<floatx4*>(out + base + (size_t)HW));
    __builtin_nontemporal_store(bo4, reinterpret_cast<floatx4*>(out + base + 2 * (size_t)HW));
}

extern "C" void kernel_launch(void* const* d_in, const int* in_sizes, int n_in,
                              void* d_out, int out_size, void* d_ws, size_t ws_size,
                              hipStream_t stream) {
    const float* img    = (const float*)d_in[0];
    const float* params = (const float*)d_in[1];
    float*       out    = (float*)d_out;

    int total_elems = in_sizes[0];          // B*3*H*W
    int Bn          = in_sizes[1] / 2;      // 64
    int HW          = total_elems / (3 * Bn);
    int quads       = HW / 4;               // HW divisible by 4 (W=512)
    int blocksPerImg = (quads + 255) / 256; // 256 quads (one block) per step

    int grid = Bn * blocksPerImg;           // 64 * 256 = 16384 for 512x512
    AdjustHueSaturation_60455959658579_kernel<<<grid, 256, 0, stream>>>(
        img, params, out, HW, quads, blocksPerImg);
}